// Round 1
// 381.441 us; speedup vs baseline: 1.0928x; 1.0928x over previous
//
#include <hip/hip_runtime.h>

#define B_  16
#define S_  1024
#define D_  384
#define QK_ 64

typedef __attribute__((ext_vector_type(8))) short bf16x8;
typedef __attribute__((ext_vector_type(4))) short bf16x4;
typedef __attribute__((ext_vector_type(4))) float f32x4;

__device__ __forceinline__ short f2bf(float f) {
  union { float f; unsigned u; } v; v.f = f;
  unsigned r = v.u + 0x7FFFu + ((v.u >> 16) & 1u);   // round-to-nearest-even
  return (short)(r >> 16);
}

__device__ __forceinline__ bf16x4 cvt4(const float4 v) {
  bf16x4 r;
  r[0] = f2bf(v.x); r[1] = f2bf(v.y); r[2] = f2bf(v.z); r[3] = f2bf(v.w);
  return r;
}

// ---------------------------------------------------------------------------
// K1: per-position projection. Grid = 2*S_: block (pos, half). half 0 -> Q,
// half 1 -> K. Weights have ZERO reuse -> no LDS staging for them: each lane
// reads its own B-fragment (32B contiguous per lane, 128B segments per wave)
// straight from global with cvt. Only x (reused across all 12 K-steps) is
// staged in LDS. No barriers in the K-loop.
// ---------------------------------------------------------------------------
__global__ __launch_bounds__(256) void k_proj(
    const float* __restrict__ x, const float* __restrict__ qw,
    const float* __restrict__ qb, const float* __restrict__ kw,
    unsigned short* __restrict__ Qb, unsigned short* __restrict__ Kb) {
  __shared__ __attribute__((aligned(16))) short xs[16 * 392];

  const int pos  = blockIdx.x >> 1;
  const int half = blockIdx.x & 1;
  const int tid  = threadIdx.x;
  const int lane = tid & 63;
  const int w    = tid >> 6;
  const int col  = lane & 15;
  const int quad = lane >> 4;

#pragma unroll
  for (int r = 0; r < 6; ++r) {
    int li = tid + 256 * r;
    int brow = li / 96, c4 = li % 96;
    float4 v = *(const float4*)&x[(brow * S_ + pos) * D_ + 4 * c4];
    *(bf16x4*)&xs[brow * 392 + 4 * c4] = cvt4(v);
  }
  __syncthreads();

  const float* wsrc = half ? kw : qw;
  const int j = w * 16 + col;                        // 0..63 (this half)
  const float* wrow = &wsrc[((size_t)pos * QK_ + j) * D_];

  f32x4 acc = {0.f, 0.f, 0.f, 0.f};
#pragma unroll
  for (int ks = 0; ks < 12; ++ks) {
    bf16x8 aF = *(const bf16x8*)&xs[col * 392 + ks * 32 + quad * 8];
    float4 w0 = *(const float4*)&wrow[ks * 32 + quad * 8];
    float4 w1 = *(const float4*)&wrow[ks * 32 + quad * 8 + 4];
    bf16x4 lo = cvt4(w0), hi = cvt4(w1);
    bf16x8 bF;
    bF[0] = lo[0]; bF[1] = lo[1]; bF[2] = lo[2]; bF[3] = lo[3];
    bF[4] = hi[0]; bF[5] = hi[1]; bF[6] = hi[2]; bF[7] = hi[3];
    acc = __builtin_amdgcn_mfma_f32_16x16x32_bf16(aF, bF, acc, 0, 0, 0);
  }

  const float SCALE = 0.051031036307982884f;   // 384^-0.5
#pragma unroll
  for (int r = 0; r < 4; ++r) {
    const int brow = quad * 4 + r;             // C/D: row = quad*4 + reg
    float v = acc[r];
    if (half == 0) {
      v = SCALE * (v + qb[pos * QK_ + j]);
      Qb[(brow * S_ + pos) * QK_ + j] = (unsigned short)f2bf(v);
    } else {
      Kb[(brow * S_ + pos) * QK_ + j] = (unsigned short)f2bf(v);
    }
  }
}

// ---------------------------------------------------------------------------
// K-XT: one-time transpose x[b][j][c] fp32 -> Xt[b][c][j] bf16. Classic
// 32x32 tile via padded LDS (stride 33 floats -> conflict-free both sides).
// ---------------------------------------------------------------------------
__global__ __launch_bounds__(256) void k_xt(
    const float* __restrict__ x, unsigned short* __restrict__ Xt) {
  __shared__ float T[32][33];
  const int gid = blockIdx.x;
  const int b  = gid / (32 * 12);
  const int r  = gid % (32 * 12);
  const int jt = r / 12, ct = r % 12;
  const int j0 = jt * 32, c0 = ct * 32;
  const int tx = threadIdx.x & 31, ty = threadIdx.x >> 5;   // ty 0..7
#pragma unroll
  for (int k = 0; k < 4; ++k)
    T[ty + 8 * k][tx] = x[(size_t)(b * S_ + j0 + ty + 8 * k) * D_ + c0 + tx];
  __syncthreads();
#pragma unroll
  for (int k = 0; k < 4; ++k) {
    int c = ty + 8 * k;
    Xt[((size_t)b * D_ + c0 + c) * S_ + j0 + tx] = (unsigned short)f2bf(T[tx][c]);
  }
}

// ---------------------------------------------------------------------------
// K2: logits = Q K^T + attn_bias. XCD-chunk swizzle: the 16 jt-siblings
// sharing a Q tile land on one XCD.
// ---------------------------------------------------------------------------
__global__ __launch_bounds__(256) void k_logits(
    const unsigned short* __restrict__ Qb, const unsigned short* __restrict__ Kb,
    const float* __restrict__ bias, float* __restrict__ attn) {
  __shared__ __attribute__((aligned(16))) short Qs[64 * 72];
  __shared__ __attribute__((aligned(16))) short Ks[64 * 72];
  const int gid0 = blockIdx.x;
  const int gid  = (gid0 & 7) * 512 + (gid0 >> 3);   // 4096 % 8 == 0, bijective
  const int b = gid >> 8, it = (gid >> 4) & 15, jt = gid & 15;
  const int i0 = it * 64, j0 = jt * 64;
  const int tid = threadIdx.x, lane = tid & 63, w = tid >> 6;
  const int col = lane & 15, quad = lane >> 4;

#pragma unroll
  for (int r = 0; r < 2; ++r) {
    int li = tid + 256 * r;
    int row = li >> 3, q8 = li & 7;
    *(uint4*)&Qs[row * 72 + q8 * 8] =
        *(const uint4*)&Qb[(b * S_ + i0 + row) * QK_ + q8 * 8];
    *(uint4*)&Ks[row * 72 + q8 * 8] =
        *(const uint4*)&Kb[(b * S_ + j0 + row) * QK_ + q8 * 8];
  }
  __syncthreads();

  f32x4 acc[4] = {{0.f,0.f,0.f,0.f},{0.f,0.f,0.f,0.f},
                  {0.f,0.f,0.f,0.f},{0.f,0.f,0.f,0.f}};
#pragma unroll
  for (int ks = 0; ks < 2; ++ks) {
    bf16x8 aF = *(const bf16x8*)&Qs[(w * 16 + col) * 72 + ks * 32 + quad * 8];
#pragma unroll
    for (int s = 0; s < 4; ++s) {
      bf16x8 bF = *(const bf16x8*)&Ks[(s * 16 + col) * 72 + ks * 32 + quad * 8];
      acc[s] = __builtin_amdgcn_mfma_f32_16x16x32_bf16(aF, bF, acc[s], 0, 0, 0);
    }
  }
#pragma unroll
  for (int s = 0; s < 4; ++s) {
    const int j = j0 + s * 16 + col;
#pragma unroll
    for (int r = 0; r < 4; ++r) {
      const int i = i0 + w * 16 + quad * 4 + r;
      attn[(size_t)(b * S_ + i) * S_ + j] = acc[s][r] + bias[i * S_ + j];
    }
  }
}

// ---------------------------------------------------------------------------
// K3: in-place row softmax over 1024 logits. One block per (b,i) row.
// ---------------------------------------------------------------------------
__global__ __launch_bounds__(256) void k_softmax(float* __restrict__ attn) {
  const int tid = threadIdx.x, lane = tid & 63, w = tid >> 6;
  float* p = attn + (size_t)blockIdx.x * S_;
  float4 v = *(const float4*)&p[tid * 4];
  float m = fmaxf(fmaxf(v.x, v.y), fmaxf(v.z, v.w));
#pragma unroll
  for (int off = 32; off > 0; off >>= 1) m = fmaxf(m, __shfl_xor(m, off));
  __shared__ float redm[4], reds[4];
  if (lane == 0) redm[w] = m;
  __syncthreads();
  m = fmaxf(fmaxf(redm[0], redm[1]), fmaxf(redm[2], redm[3]));
  float4 e;
  e.x = __expf(v.x - m); e.y = __expf(v.y - m);
  e.z = __expf(v.z - m); e.w = __expf(v.w - m);
  float s = e.x + e.y + e.z + e.w;
#pragma unroll
  for (int off = 32; off > 0; off >>= 1) s += __shfl_xor(s, off);
  if (lane == 0) reds[w] = s;
  __syncthreads();
  s = reds[0] + reds[1] + reds[2] + reds[3];
  const float inv = 1.0f / s;
  e.x *= inv; e.y *= inv; e.z *= inv; e.w *= inv;
  *(float4*)&p[tid * 4] = e;
}

// ---------------------------------------------------------------------------
// K4: out = P @ X per batch. Block = 64 i x 128 c, j-step 64. X pre-transposed
// bf16 -> staging is pure 16B vector copies; LDS rows padded to 72 shorts
// (144B) -> conflict-free writes AND reads (mod-128 positions uniform).
// Register prefetch overlaps global loads with MFMAs. XCD-chunk swizzle
// keeps the 3 ct-siblings (same P panel) on one XCD.
// ---------------------------------------------------------------------------
__global__ __launch_bounds__(256) void k_out(
    const float* __restrict__ attn, const unsigned short* __restrict__ Xt,
    float* __restrict__ out) {
  __shared__ __attribute__((aligned(16))) short Ps[64 * 72];   // [i][j] bf16
  __shared__ __attribute__((aligned(16))) short Xs[128 * 72];  // [c][j] bf16
  const int gid0 = blockIdx.x;
  const int gid  = (gid0 & 7) * 96 + (gid0 >> 3);   // 768 % 8 == 0, bijective
  const int b = gid / 48, r48 = gid % 48;
  const int it = r48 / 3, ct = r48 % 3;
  const int i0 = it * 64, c0 = ct * 128;
  const int tid = threadIdx.x, lane = tid & 63, w = tid >> 6;
  const int col = lane & 15, quad = lane >> 4;

  const float* pA = &attn[(size_t)(b * S_ + i0) * S_];
  const unsigned short* xA = &Xt[((size_t)b * D_ + c0) * S_];

  f32x4 acc[8] = {{0.f,0.f,0.f,0.f},{0.f,0.f,0.f,0.f},{0.f,0.f,0.f,0.f},
                  {0.f,0.f,0.f,0.f},{0.f,0.f,0.f,0.f},{0.f,0.f,0.f,0.f},
                  {0.f,0.f,0.f,0.f},{0.f,0.f,0.f,0.f}};

  float4 pv[4];   // P prefetch: 64 i rows x 16 float4 (j)
  uint4  xv[4];   // X prefetch: 128 c rows x 8 uint4 (j)

#pragma unroll
  for (int r = 0; r < 4; ++r) {
    int li = tid + 256 * r;
    { int ii = li >> 4, f4 = li & 15;
      pv[r] = *(const float4*)&pA[(size_t)ii * S_ + f4 * 4]; }
    { int cc = li >> 3, p8 = li & 7;
      xv[r] = *(const uint4*)&xA[(size_t)cc * S_ + p8 * 8]; }
  }

  for (int t = 0; t < 16; ++t) {
    __syncthreads();   // previous-iteration LDS reads done
#pragma unroll
    for (int r = 0; r < 4; ++r) {
      int li = tid + 256 * r;
      int ii = li >> 4, f4 = li & 15;
      *(bf16x4*)&Ps[ii * 72 + f4 * 4] = cvt4(pv[r]);
    }
#pragma unroll
    for (int r = 0; r < 4; ++r) {
      int li = tid + 256 * r;
      int cc = li >> 3, p8 = li & 7;
      *(uint4*)&Xs[cc * 72 + p8 * 8] = xv[r];
    }
    __syncthreads();   // tile ready
    if (t < 15) {      // issue next-tile loads; overlap with MFMAs below
      const int j1 = (t + 1) * 64;
#pragma unroll
      for (int r = 0; r < 4; ++r) {
        int li = tid + 256 * r;
        { int ii = li >> 4, f4 = li & 15;
          pv[r] = *(const float4*)&pA[(size_t)ii * S_ + j1 + f4 * 4]; }
        { int cc = li >> 3, p8 = li & 7;
          xv[r] = *(const uint4*)&xA[(size_t)cc * S_ + j1 + p8 * 8]; }
      }
    }
#pragma unroll
    for (int ks = 0; ks < 2; ++ks) {
      bf16x8 aF = *(const bf16x8*)&Ps[(w * 16 + col) * 72 + ks * 32 + quad * 8];
#pragma unroll
      for (int s = 0; s < 8; ++s) {
        bf16x8 bF = *(const bf16x8*)&Xs[(s * 16 + col) * 72 + ks * 32 + quad * 8];
        acc[s] = __builtin_amdgcn_mfma_f32_16x16x32_bf16(aF, bF, acc[s], 0, 0, 0);
      }
    }
  }

#pragma unroll
  for (int s = 0; s < 8; ++s) {
    const int c = c0 + s * 16 + col;
#pragma unroll
    for (int r = 0; r < 4; ++r) {
      const int i = i0 + w * 16 + quad * 4 + r;
      out[(size_t)(b * S_ + i) * D_ + c] = acc[s][r];
    }
  }
}

extern "C" void kernel_launch(void* const* d_in, const int* in_sizes, int n_in,
                              void* d_out, int out_size, void* d_ws, size_t ws_size,
                              hipStream_t stream) {
  const float* x  = (const float*)d_in[0];
  const float* qw = (const float*)d_in[1];
  const float* qb = (const float*)d_in[2];
  const float* kw = (const float*)d_in[3];
  const float* ab = (const float*)d_in[4];

  float* out  = (float*)d_out;
  float* attn = out + (size_t)B_ * S_ * D_;          // outputs concatenated

  unsigned short* Qb = (unsigned short*)d_ws;        // bf16 Q [B][S][64]
  unsigned short* Kb = Qb + (size_t)B_ * S_ * QK_;   // bf16 K [B][S][64]
  unsigned short* Xt = Kb + (size_t)B_ * S_ * QK_;   // bf16 X^T [B][384][1024]

  k_proj   <<<2 * S_,        256, 0, stream>>>(x, qw, qb, kw, Qb, Kb);
  k_xt     <<<B_ * 32 * 12,  256, 0, stream>>>(x, Xt);
  k_logits <<<B_ * 16 * 16,  256, 0, stream>>>(Qb, Kb, ab, attn);
  k_softmax<<<B_ * S_,       256, 0, stream>>>(attn);
  k_out    <<<B_ * 16 * 3,   256, 0, stream>>>(attn, Xt, out);
}

// Round 2
// 381.122 us; speedup vs baseline: 1.0937x; 1.0008x over previous
//
#include <hip/hip_runtime.h>

#define B_  16
#define S_  1024
#define D_  384
#define QK_ 64

typedef __attribute__((ext_vector_type(8))) short bf16x8;
typedef __attribute__((ext_vector_type(4))) short bf16x4;
typedef __attribute__((ext_vector_type(4))) float f32x4;

__device__ __forceinline__ short f2bf(float f) {
  union { float f; unsigned u; } v; v.f = f;
  unsigned r = v.u + 0x7FFFu + ((v.u >> 16) & 1u);   // round-to-nearest-even
  return (short)(r >> 16);
}

__device__ __forceinline__ bf16x4 cvt4(const float4 v) {
  bf16x4 r;
  r[0] = f2bf(v.x); r[1] = f2bf(v.y); r[2] = f2bf(v.z); r[3] = f2bf(v.w);
  return r;
}

// ---------------------------------------------------------------------------
// K1: per-position projection. Grid = 2*S_: block (pos, half); half 0 -> Q,
// half 1 -> K. Weights have zero reuse -> read straight from global into a
// 4-step-deep rolling register window (8 float4 in flight per lane) so the
// wave is never latency-blocked on a single dependent load->cvt->mfma chain.
// x (reused by all 12 K-steps) staged once in LDS.
// ---------------------------------------------------------------------------
__global__ __launch_bounds__(256) void k_proj(
    const float* __restrict__ x, const float* __restrict__ qw,
    const float* __restrict__ qb, const float* __restrict__ kw,
    unsigned short* __restrict__ Qb, unsigned short* __restrict__ Kb) {
  __shared__ __attribute__((aligned(16))) short xs[16 * 392];

  const int pos  = blockIdx.x >> 1;
  const int half = blockIdx.x & 1;
  const int tid  = threadIdx.x;
  const int lane = tid & 63;
  const int w    = tid >> 6;
  const int col  = lane & 15;
  const int quad = lane >> 4;

  // issue x staging loads first (their waits then don't drain the w-loads)
  float4 xv[6];
#pragma unroll
  for (int r = 0; r < 6; ++r) {
    int li = tid + 256 * r;
    int brow = li / 96, c4 = li % 96;
    xv[r] = *(const float4*)&x[(brow * S_ + pos) * D_ + 4 * c4];
  }

  const float* wsrc = half ? kw : qw;
  const int j = w * 16 + col;                        // 0..63 (this half)
  const float* wrow = &wsrc[((size_t)pos * QK_ + j) * D_];

  // weight prefetch window: slots for ks, ks+1, ks+2, ks+3
  float4 wv[8];
#pragma unroll
  for (int ks = 0; ks < 4; ++ks) {
    wv[2 * ks]     = *(const float4*)&wrow[ks * 32 + quad * 8];
    wv[2 * ks + 1] = *(const float4*)&wrow[ks * 32 + quad * 8 + 4];
  }

#pragma unroll
  for (int r = 0; r < 6; ++r) {
    int li = tid + 256 * r;
    int brow = li / 96, c4 = li % 96;
    *(bf16x4*)&xs[brow * 392 + 4 * c4] = cvt4(xv[r]);
  }
  __syncthreads();

  f32x4 acc = {0.f, 0.f, 0.f, 0.f};
#pragma unroll
  for (int ks = 0; ks < 12; ++ks) {
    const int sl = ks & 3;
    bf16x8 aF = *(const bf16x8*)&xs[col * 392 + ks * 32 + quad * 8];
    bf16x4 lo = cvt4(wv[2 * sl]), hi = cvt4(wv[2 * sl + 1]);
    if (ks < 8) {  // refill slot with ks+4 before it's needed again
      wv[2 * sl]     = *(const float4*)&wrow[(ks + 4) * 32 + quad * 8];
      wv[2 * sl + 1] = *(const float4*)&wrow[(ks + 4) * 32 + quad * 8 + 4];
    }
    bf16x8 bF;
    bF[0] = lo[0]; bF[1] = lo[1]; bF[2] = lo[2]; bF[3] = lo[3];
    bF[4] = hi[0]; bF[5] = hi[1]; bF[6] = hi[2]; bF[7] = hi[3];
    acc = __builtin_amdgcn_mfma_f32_16x16x32_bf16(aF, bF, acc, 0, 0, 0);
  }

  const float SCALE = 0.051031036307982884f;   // 384^-0.5
#pragma unroll
  for (int r = 0; r < 4; ++r) {
    const int brow = quad * 4 + r;             // C/D: row = quad*4 + reg
    float v = acc[r];
    if (half == 0) {
      v = SCALE * (v + qb[pos * QK_ + j]);
      Qb[(brow * S_ + pos) * QK_ + j] = (unsigned short)f2bf(v);
    } else {
      Kb[(brow * S_ + pos) * QK_ + j] = (unsigned short)f2bf(v);
    }
  }
}

// ---------------------------------------------------------------------------
// K-XT: one-time transpose x[b][j][c] fp32 -> Xt[b][c][j] bf16. Classic
// 32x32 tile via padded LDS (stride 33 floats -> conflict-free both sides).
// ---------------------------------------------------------------------------
__global__ __launch_bounds__(256) void k_xt(
    const float* __restrict__ x, unsigned short* __restrict__ Xt) {
  __shared__ float T[32][33];
  const int gid = blockIdx.x;
  const int b  = gid / (32 * 12);
  const int r  = gid % (32 * 12);
  const int jt = r / 12, ct = r % 12;
  const int j0 = jt * 32, c0 = ct * 32;
  const int tx = threadIdx.x & 31, ty = threadIdx.x >> 5;   // ty 0..7
#pragma unroll
  for (int k = 0; k < 4; ++k)
    T[ty + 8 * k][tx] = x[(size_t)(b * S_ + j0 + ty + 8 * k) * D_ + c0 + tx];
  __syncthreads();
#pragma unroll
  for (int k = 0; k < 4; ++k) {
    int c = ty + 8 * k;
    Xt[((size_t)b * D_ + c0 + c) * S_ + j0 + tx] = (unsigned short)f2bf(T[tx][c]);
  }
}

// ---------------------------------------------------------------------------
// K-ATTN: fused logits + bias + softmax. One wave per 16 Q-rows.
// Two-pass over K tiles: pass 1 computes QK^T tiles (MFMA, operands read
// straight from L2-resident Qb/Kb -- no LDS, no barriers) tracking online
// row max m and denominator l in registers; pass 2 recomputes the identical
// MFMAs (4 GFLOP total, trivial) and writes normalized P = exp(s-m)/l once.
// Replaces k_logits + k_softmax: deletes a 64MB write + 64MB read + 64MB
// write round-trip of the attn matrix.
// ---------------------------------------------------------------------------
__global__ __launch_bounds__(64) void k_attn(
    const unsigned short* __restrict__ Qb, const unsigned short* __restrict__ Kb,
    const float* __restrict__ bias, float* __restrict__ attn) {
  const int gid   = blockIdx.x;          // b*64 + itile
  const int b     = gid >> 6;
  const int i0    = (gid & 63) * 16;
  const int lane  = threadIdx.x & 63;
  const int col   = lane & 15, quad = lane >> 4;
  const int iq    = i0 + quad * 4;       // this lane's acc rows: iq..iq+3

  // Q fragment (A-operand rows indexed by col), hoisted for both K-steps
  const unsigned short* qp = &Qb[(size_t)(b * S_ + i0 + col) * QK_];
  const bf16x8 qf0 = *(const bf16x8*)&qp[quad * 8];
  const bf16x8 qf1 = *(const bf16x8*)&qp[32 + quad * 8];

  float m[4] = {-3.0e38f, -3.0e38f, -3.0e38f, -3.0e38f};
  float l[4] = {0.f, 0.f, 0.f, 0.f};

  // ---- pass 1: online max + denominator, nothing stored ----
  for (int jt = 0; jt < 16; ++jt) {
    const int j0 = jt * 64;
    const unsigned short* kp = &Kb[(size_t)(b * S_ + j0 + col) * QK_];
    f32x4 acc[4] = {{0.f,0.f,0.f,0.f},{0.f,0.f,0.f,0.f},
                    {0.f,0.f,0.f,0.f},{0.f,0.f,0.f,0.f}};
#pragma unroll
    for (int s = 0; s < 4; ++s) {
      bf16x8 k0 = *(const bf16x8*)&kp[(s * 16) * QK_ + quad * 8];
      bf16x8 k1 = *(const bf16x8*)&kp[(s * 16) * QK_ + 32 + quad * 8];
      acc[s] = __builtin_amdgcn_mfma_f32_16x16x32_bf16(qf0, k0, acc[s], 0, 0, 0);
      acc[s] = __builtin_amdgcn_mfma_f32_16x16x32_bf16(qf1, k1, acc[s], 0, 0, 0);
    }
#pragma unroll
    for (int r = 0; r < 4; ++r) {
      float sv0 = acc[0][r] + bias[(size_t)(iq + r) * S_ + j0 + 0 * 16 + col];
      float sv1 = acc[1][r] + bias[(size_t)(iq + r) * S_ + j0 + 1 * 16 + col];
      float sv2 = acc[2][r] + bias[(size_t)(iq + r) * S_ + j0 + 2 * 16 + col];
      float sv3 = acc[3][r] + bias[(size_t)(iq + r) * S_ + j0 + 3 * 16 + col];
      float t = fmaxf(fmaxf(sv0, sv1), fmaxf(sv2, sv3));
#pragma unroll
      for (int off = 8; off >= 1; off >>= 1) t = fmaxf(t, __shfl_xor(t, off));
      const float mn = fmaxf(m[r], t);
      float sum = __expf(sv0 - mn) + __expf(sv1 - mn) +
                  __expf(sv2 - mn) + __expf(sv3 - mn);
#pragma unroll
      for (int off = 8; off >= 1; off >>= 1) sum += __shfl_xor(sum, off);
      l[r] = l[r] * __expf(m[r] - mn) + sum;
      m[r] = mn;
    }
  }

  float inv[4];
#pragma unroll
  for (int r = 0; r < 4; ++r) inv[r] = 1.0f / l[r];

  // ---- pass 2: recompute tiles (bitwise-identical MFMAs), write P once ----
  for (int jt = 0; jt < 16; ++jt) {
    const int j0 = jt * 64;
    const unsigned short* kp = &Kb[(size_t)(b * S_ + j0 + col) * QK_];
    f32x4 acc[4] = {{0.f,0.f,0.f,0.f},{0.f,0.f,0.f,0.f},
                    {0.f,0.f,0.f,0.f},{0.f,0.f,0.f,0.f}};
#pragma unroll
    for (int s = 0; s < 4; ++s) {
      bf16x8 k0 = *(const bf16x8*)&kp[(s * 16) * QK_ + quad * 8];
      bf16x8 k1 = *(const bf16x8*)&kp[(s * 16) * QK_ + 32 + quad * 8];
      acc[s] = __builtin_amdgcn_mfma_f32_16x16x32_bf16(qf0, k0, acc[s], 0, 0, 0);
      acc[s] = __builtin_amdgcn_mfma_f32_16x16x32_bf16(qf1, k1, acc[s], 0, 0, 0);
    }
#pragma unroll
    for (int r = 0; r < 4; ++r) {
#pragma unroll
      for (int s = 0; s < 4; ++s) {
        const float sv = acc[s][r] +
            bias[(size_t)(iq + r) * S_ + j0 + s * 16 + col];
        attn[(size_t)(b * S_ + iq + r) * S_ + j0 + s * 16 + col] =
            __expf(sv - m[r]) * inv[r];
      }
    }
  }
}

// ---------------------------------------------------------------------------
// K4: out = P @ X per batch. Block = 64 i x 128 c, j-step 64. X pre-transposed
// bf16 -> staging is pure 16B vector copies; LDS rows padded to 72 shorts
// (144B) -> conflict-free writes AND reads. Register prefetch overlaps global
// loads with MFMAs. XCD-chunk swizzle keeps the 3 ct-siblings on one XCD.
// ---------------------------------------------------------------------------
__global__ __launch_bounds__(256) void k_out(
    const float* __restrict__ attn, const unsigned short* __restrict__ Xt,
    float* __restrict__ out) {
  __shared__ __attribute__((aligned(16))) short Ps[64 * 72];   // [i][j] bf16
  __shared__ __attribute__((aligned(16))) short Xs[128 * 72];  // [c][j] bf16
  const int gid0 = blockIdx.x;
  const int gid  = (gid0 & 7) * 96 + (gid0 >> 3);   // 768 % 8 == 0, bijective
  const int b = gid / 48, r48 = gid % 48;
  const int it = r48 / 3, ct = r48 % 3;
  const int i0 = it * 64, c0 = ct * 128;
  const int tid = threadIdx.x, lane = tid & 63, w = tid >> 6;
  const int col = lane & 15, quad = lane >> 4;

  const float* pA = &attn[(size_t)(b * S_ + i0) * S_];
  const unsigned short* xA = &Xt[((size_t)b * D_ + c0) * S_];

  f32x4 acc[8] = {{0.f,0.f,0.f,0.f},{0.f,0.f,0.f,0.f},{0.f,0.f,0.f,0.f},
                  {0.f,0.f,0.f,0.f},{0.f,0.f,0.f,0.f},{0.f,0.f,0.f,0.f},
                  {0.f,0.f,0.f,0.f},{0.f,0.f,0.f,0.f}};

  float4 pv[4];   // P prefetch: 64 i rows x 16 float4 (j)
  uint4  xv[4];   // X prefetch: 128 c rows x 8 uint4 (j)

#pragma unroll
  for (int r = 0; r < 4; ++r) {
    int li = tid + 256 * r;
    { int ii = li >> 4, f4 = li & 15;
      pv[r] = *(const float4*)&pA[(size_t)ii * S_ + f4 * 4]; }
    { int cc = li >> 3, p8 = li & 7;
      xv[r] = *(const uint4*)&xA[(size_t)cc * S_ + p8 * 8]; }
  }

  for (int t = 0; t < 16; ++t) {
    __syncthreads();   // previous-iteration LDS reads done
#pragma unroll
    for (int r = 0; r < 4; ++r) {
      int li = tid + 256 * r;
      int ii = li >> 4, f4 = li & 15;
      *(bf16x4*)&Ps[ii * 72 + f4 * 4] = cvt4(pv[r]);
    }
#pragma unroll
    for (int r = 0; r < 4; ++r) {
      int li = tid + 256 * r;
      int cc = li >> 3, p8 = li & 7;
      *(uint4*)&Xs[cc * 72 + p8 * 8] = xv[r];
    }
    __syncthreads();   // tile ready
    if (t < 15) {      // issue next-tile loads; overlap with MFMAs below
      const int j1 = (t + 1) * 64;
#pragma unroll
      for (int r = 0; r < 4; ++r) {
        int li = tid + 256 * r;
        { int ii = li >> 4, f4 = li & 15;
          pv[r] = *(const float4*)&pA[(size_t)ii * S_ + j1 + f4 * 4]; }
        { int cc = li >> 3, p8 = li & 7;
          xv[r] = *(const uint4*)&xA[(size_t)cc * S_ + j1 + p8 * 8]; }
      }
    }
#pragma unroll
    for (int ks = 0; ks < 2; ++ks) {
      bf16x8 aF = *(const bf16x8*)&Ps[(w * 16 + col) * 72 + ks * 32 + quad * 8];
#pragma unroll
      for (int s = 0; s < 8; ++s) {
        bf16x8 bF = *(const bf16x8*)&Xs[(s * 16 + col) * 72 + ks * 32 + quad * 8];
        acc[s] = __builtin_amdgcn_mfma_f32_16x16x32_bf16(aF, bF, acc[s], 0, 0, 0);
      }
    }
  }

#pragma unroll
  for (int s = 0; s < 8; ++s) {
    const int c = c0 + s * 16 + col;
#pragma unroll
    for (int r = 0; r < 4; ++r) {
      const int i = i0 + w * 16 + quad * 4 + r;
      out[(size_t)(b * S_ + i) * D_ + c] = acc[s][r];
    }
  }
}

extern "C" void kernel_launch(void* const* d_in, const int* in_sizes, int n_in,
                              void* d_out, int out_size, void* d_ws, size_t ws_size,
                              hipStream_t stream) {
  const float* x  = (const float*)d_in[0];
  const float* qw = (const float*)d_in[1];
  const float* qb = (const float*)d_in[2];
  const float* kw = (const float*)d_in[3];
  const float* ab = (const float*)d_in[4];

  float* out  = (float*)d_out;
  float* attn = out + (size_t)B_ * S_ * D_;          // outputs concatenated

  unsigned short* Qb = (unsigned short*)d_ws;        // bf16 Q [B][S][64]
  unsigned short* Kb = Qb + (size_t)B_ * S_ * QK_;   // bf16 K [B][S][64]
  unsigned short* Xt = Kb + (size_t)B_ * S_ * QK_;   // bf16 X^T [B][384][1024]

  k_proj <<<2 * S_,       256, 0, stream>>>(x, qw, qb, kw, Qb, Kb);
  k_xt   <<<B_ * 32 * 12, 256, 0, stream>>>(x, Xt);
  k_attn <<<B_ * 64,       64, 0, stream>>>(Qb, Kb, ab, attn);
  k_out  <<<B_ * 16 * 3,  256, 0, stream>>>(attn, Xt, out);
}

// Round 3
// 364.360 us; speedup vs baseline: 1.1440x; 1.0460x over previous
//
#include <hip/hip_runtime.h>

#define B_  16
#define S_  1024
#define D_  384
#define QK_ 64

typedef __attribute__((ext_vector_type(8))) short bf16x8;
typedef __attribute__((ext_vector_type(4))) short bf16x4;
typedef __attribute__((ext_vector_type(4))) float f32x4;

__device__ __forceinline__ short f2bf(float f) {
  union { float f; unsigned u; } v; v.f = f;
  unsigned r = v.u + 0x7FFFu + ((v.u >> 16) & 1u);   // round-to-nearest-even
  return (short)(r >> 16);
}

__device__ __forceinline__ bf16x4 cvt4(const float4 v) {
  bf16x4 r;
  r[0] = f2bf(v.x); r[1] = f2bf(v.y); r[2] = f2bf(v.z); r[3] = f2bf(v.w);
  return r;
}

// ---------------------------------------------------------------------------
// K1: per-position projection. Grid = 2*S_: block (pos, half); half 0 -> Q,
// half 1 -> K. Weights have zero reuse -> each lane loads its ENTIRE weight
// row (24 float4) into individually-NAMED registers up front (no arrays ->
// nothing the compiler can sink or spill), then 12 hand-unrolled MFMA steps
// consume them in issue order (progressive vmcnt drain). x staging loads are
// issued before the weight batch so their wait doesn't drain the queue.
// ---------------------------------------------------------------------------
__global__ __launch_bounds__(256) void k_proj(
    const float* __restrict__ x, const float* __restrict__ qw,
    const float* __restrict__ qb, const float* __restrict__ kw,
    unsigned short* __restrict__ Qb, unsigned short* __restrict__ Kb) {
  __shared__ __attribute__((aligned(16))) short xs[16 * 392];

  const int pos  = blockIdx.x >> 1;
  const int half = blockIdx.x & 1;
  const int tid  = threadIdx.x;
  const int lane = tid & 63;
  const int w    = tid >> 6;
  const int col  = lane & 15;
  const int quad = lane >> 4;

  // --- issue x staging loads first (oldest in queue) ---
  float4 xv0, xv1, xv2, xv3, xv4, xv5;
#define XL(r, dst) { const int li = tid + 256 * (r);                        \
    const int brow = li / 96, c4 = li % 96;                                 \
    dst = *(const float4*)&x[(brow * S_ + pos) * D_ + 4 * c4]; }
  XL(0, xv0) XL(1, xv1) XL(2, xv2) XL(3, xv3) XL(4, xv4) XL(5, xv5)
#undef XL

  const float* wsrc = half ? kw : qw;
  const int j = w * 16 + col;                        // 0..63 (this half)
  const float* wrow = &wsrc[((size_t)pos * QK_ + j) * D_];

  // --- issue ALL 24 weight loads (named registers, in ks order) ---
  float4 wA0, wB0, wA1, wB1, wA2,  wB2,  wA3,  wB3,  wA4,  wB4,  wA5,  wB5,
         wA6, wB6, wA7, wB7, wA8,  wB8,  wA9,  wB9,  wA10, wB10, wA11, wB11;
#define WL(k)                                                               \
  wA##k = *(const float4*)&wrow[(k) * 32 + quad * 8];                       \
  wB##k = *(const float4*)&wrow[(k) * 32 + quad * 8 + 4];
  WL(0) WL(1) WL(2) WL(3) WL(4) WL(5) WL(6) WL(7) WL(8) WL(9) WL(10) WL(11)
#undef WL

  // --- convert + stage x (waits only the 6 oldest loads) ---
#define XS(r, src) { const int li = tid + 256 * (r);                        \
    const int brow = li / 96, c4 = li % 96;                                 \
    *(bf16x4*)&xs[brow * 392 + 4 * c4] = cvt4(src); }
  XS(0, xv0) XS(1, xv1) XS(2, xv2) XS(3, xv3) XS(4, xv4) XS(5, xv5)
#undef XS
  __syncthreads();

  f32x4 acc = {0.f, 0.f, 0.f, 0.f};
#define STEP(k) {                                                           \
    bf16x8 aF = *(const bf16x8*)&xs[col * 392 + (k) * 32 + quad * 8];       \
    bf16x4 lo = cvt4(wA##k), hi = cvt4(wB##k);                              \
    bf16x8 bF;                                                              \
    bF[0] = lo[0]; bF[1] = lo[1]; bF[2] = lo[2]; bF[3] = lo[3];             \
    bF[4] = hi[0]; bF[5] = hi[1]; bF[6] = hi[2]; bF[7] = hi[3];             \
    acc = __builtin_amdgcn_mfma_f32_16x16x32_bf16(aF, bF, acc, 0, 0, 0); }
  STEP(0) STEP(1) STEP(2) STEP(3) STEP(4)  STEP(5)
  STEP(6) STEP(7) STEP(8) STEP(9) STEP(10) STEP(11)
#undef STEP

  const float SCALE = 0.051031036307982884f;   // 384^-0.5
#pragma unroll
  for (int r = 0; r < 4; ++r) {
    const int brow = quad * 4 + r;             // C/D: row = quad*4 + reg
    float v = acc[r];
    if (half == 0) {
      v = SCALE * (v + qb[pos * QK_ + j]);
      Qb[(brow * S_ + pos) * QK_ + j] = (unsigned short)f2bf(v);
    } else {
      Kb[(brow * S_ + pos) * QK_ + j] = (unsigned short)f2bf(v);
    }
  }
}

// ---------------------------------------------------------------------------
// K-XT: one-time transpose x[b][j][c] fp32 -> Xt[b][c][j] bf16. Classic
// 32x32 tile via padded LDS (stride 33 floats -> conflict-free both sides).
// ---------------------------------------------------------------------------
__global__ __launch_bounds__(256) void k_xt(
    const float* __restrict__ x, unsigned short* __restrict__ Xt) {
  __shared__ float T[32][33];
  const int gid = blockIdx.x;
  const int b  = gid / (32 * 12);
  const int r  = gid % (32 * 12);
  const int jt = r / 12, ct = r % 12;
  const int j0 = jt * 32, c0 = ct * 32;
  const int tx = threadIdx.x & 31, ty = threadIdx.x >> 5;   // ty 0..7
#pragma unroll
  for (int k = 0; k < 4; ++k)
    T[ty + 8 * k][tx] = x[(size_t)(b * S_ + j0 + ty + 8 * k) * D_ + c0 + tx];
  __syncthreads();
#pragma unroll
  for (int k = 0; k < 4; ++k) {
    int c = ty + 8 * k;
    Xt[((size_t)b * D_ + c0 + c) * S_ + j0 + tx] = (unsigned short)f2bf(T[tx][c]);
  }
}

// ---------------------------------------------------------------------------
// K-ATTN: fused logits + bias + softmax, 4 waves/block (was 1 wave/block ->
// 1 wave/SIMD, zero latency hiding). Block owns 16 Q-rows; wave w owns jt
// tiles {4w..4w+3}. Pass 1: online (m,l) per wave; LDS combine across the 4
// waves; pass 2: each wave recomputes its own tiles (identical MFMAs) and
// writes normalized P once. 4096 waves total = 4/SIMD.
// ---------------------------------------------------------------------------
__global__ __launch_bounds__(256) void k_attn(
    const unsigned short* __restrict__ Qb, const unsigned short* __restrict__ Kb,
    const float* __restrict__ bias, float* __restrict__ attn) {
  __shared__ float Ms[4][16], Ls[4][16];
  const int gid   = blockIdx.x;          // b*64 + itile
  const int b     = gid >> 6;
  const int i0    = (gid & 63) * 16;
  const int tid   = threadIdx.x;
  const int lane  = tid & 63, w = tid >> 6;
  const int col   = lane & 15, quad = lane >> 4;
  const int iq    = i0 + quad * 4;       // this lane's acc rows: iq..iq+3

  // Q fragment (A-operand rows indexed by col), hoisted for both K-steps
  const unsigned short* qp = &Qb[(size_t)(b * S_ + i0 + col) * QK_];
  const bf16x8 qf0 = *(const bf16x8*)&qp[quad * 8];
  const bf16x8 qf1 = *(const bf16x8*)&qp[32 + quad * 8];

  float m[4] = {-3.0e38f, -3.0e38f, -3.0e38f, -3.0e38f};
  float l[4] = {0.f, 0.f, 0.f, 0.f};

  // ---- pass 1: online max + denominator over this wave's 4 jt tiles ----
#pragma unroll
  for (int jj = 0; jj < 4; ++jj) {
    const int j0 = (w * 4 + jj) * 64;
    const unsigned short* kp = &Kb[(size_t)(b * S_ + j0 + col) * QK_];
    f32x4 acc[4] = {{0.f,0.f,0.f,0.f},{0.f,0.f,0.f,0.f},
                    {0.f,0.f,0.f,0.f},{0.f,0.f,0.f,0.f}};
#pragma unroll
    for (int s = 0; s < 4; ++s) {
      bf16x8 k0 = *(const bf16x8*)&kp[(s * 16) * QK_ + quad * 8];
      bf16x8 k1 = *(const bf16x8*)&kp[(s * 16) * QK_ + 32 + quad * 8];
      acc[s] = __builtin_amdgcn_mfma_f32_16x16x32_bf16(qf0, k0, acc[s], 0, 0, 0);
      acc[s] = __builtin_amdgcn_mfma_f32_16x16x32_bf16(qf1, k1, acc[s], 0, 0, 0);
    }
#pragma unroll
    for (int r = 0; r < 4; ++r) {
      float sv0 = acc[0][r] + bias[(size_t)(iq + r) * S_ + j0 + 0 * 16 + col];
      float sv1 = acc[1][r] + bias[(size_t)(iq + r) * S_ + j0 + 1 * 16 + col];
      float sv2 = acc[2][r] + bias[(size_t)(iq + r) * S_ + j0 + 2 * 16 + col];
      float sv3 = acc[3][r] + bias[(size_t)(iq + r) * S_ + j0 + 3 * 16 + col];
      float t = fmaxf(fmaxf(sv0, sv1), fmaxf(sv2, sv3));
#pragma unroll
      for (int off = 8; off >= 1; off >>= 1) t = fmaxf(t, __shfl_xor(t, off));
      const float mn = fmaxf(m[r], t);
      float sum = __expf(sv0 - mn) + __expf(sv1 - mn) +
                  __expf(sv2 - mn) + __expf(sv3 - mn);
#pragma unroll
      for (int off = 8; off >= 1; off >>= 1) sum += __shfl_xor(sum, off);
      l[r] = l[r] * __expf(m[r] - mn) + sum;
      m[r] = mn;
    }
  }

  // ---- combine partial (m,l) across the 4 waves via LDS ----
  if (col == 0) {
#pragma unroll
    for (int r = 0; r < 4; ++r) {
      Ms[w][quad * 4 + r] = m[r];
      Ls[w][quad * 4 + r] = l[r];
    }
  }
  __syncthreads();

  float gm[4], inv[4];
#pragma unroll
  for (int r = 0; r < 4; ++r) {
    const int row = quad * 4 + r;
    const float m0 = Ms[0][row], m1 = Ms[1][row];
    const float m2 = Ms[2][row], m3 = Ms[3][row];
    const float g  = fmaxf(fmaxf(m0, m1), fmaxf(m2, m3));
    const float L  = Ls[0][row] * __expf(m0 - g) + Ls[1][row] * __expf(m1 - g)
                   + Ls[2][row] * __expf(m2 - g) + Ls[3][row] * __expf(m3 - g);
    gm[r]  = g;
    inv[r] = 1.0f / L;
  }

  // ---- pass 2: recompute own tiles (identical MFMAs), write P once ----
#pragma unroll
  for (int jj = 0; jj < 4; ++jj) {
    const int j0 = (w * 4 + jj) * 64;
    const unsigned short* kp = &Kb[(size_t)(b * S_ + j0 + col) * QK_];
    f32x4 acc[4] = {{0.f,0.f,0.f,0.f},{0.f,0.f,0.f,0.f},
                    {0.f,0.f,0.f,0.f},{0.f,0.f,0.f,0.f}};
#pragma unroll
    for (int s = 0; s < 4; ++s) {
      bf16x8 k0 = *(const bf16x8*)&kp[(s * 16) * QK_ + quad * 8];
      bf16x8 k1 = *(const bf16x8*)&kp[(s * 16) * QK_ + 32 + quad * 8];
      acc[s] = __builtin_amdgcn_mfma_f32_16x16x32_bf16(qf0, k0, acc[s], 0, 0, 0);
      acc[s] = __builtin_amdgcn_mfma_f32_16x16x32_bf16(qf1, k1, acc[s], 0, 0, 0);
    }
#pragma unroll
    for (int r = 0; r < 4; ++r) {
#pragma unroll
      for (int s = 0; s < 4; ++s) {
        const float sv = acc[s][r] +
            bias[(size_t)(iq + r) * S_ + j0 + s * 16 + col];
        attn[(size_t)(b * S_ + iq + r) * S_ + j0 + s * 16 + col] =
            __expf(sv - gm[r]) * inv[r];
      }
    }
  }
}

// ---------------------------------------------------------------------------
// K4: out = P @ X per batch. Block = 64 i x 128 c, j-step 64. X pre-transposed
// bf16 -> staging is pure 16B vector copies; LDS rows padded to 72 shorts
// (144B) -> conflict-free writes AND reads. Register prefetch overlaps global
// loads with MFMAs. XCD-chunk swizzle keeps the 3 ct-siblings on one XCD.
// ---------------------------------------------------------------------------
__global__ __launch_bounds__(256) void k_out(
    const float* __restrict__ attn, const unsigned short* __restrict__ Xt,
    float* __restrict__ out) {
  __shared__ __attribute__((aligned(16))) short Ps[64 * 72];   // [i][j] bf16
  __shared__ __attribute__((aligned(16))) short Xs[128 * 72];  // [c][j] bf16
  const int gid0 = blockIdx.x;
  const int gid  = (gid0 & 7) * 96 + (gid0 >> 3);   // 768 % 8 == 0, bijective
  const int b = gid / 48, r48 = gid % 48;
  const int it = r48 / 3, ct = r48 % 3;
  const int i0 = it * 64, c0 = ct * 128;
  const int tid = threadIdx.x, lane = tid & 63, w = tid >> 6;
  const int col = lane & 15, quad = lane >> 4;

  const float* pA = &attn[(size_t)(b * S_ + i0) * S_];
  const unsigned short* xA = &Xt[((size_t)b * D_ + c0) * S_];

  f32x4 acc[8] = {{0.f,0.f,0.f,0.f},{0.f,0.f,0.f,0.f},{0.f,0.f,0.f,0.f},
                  {0.f,0.f,0.f,0.f},{0.f,0.f,0.f,0.f},{0.f,0.f,0.f,0.f},
                  {0.f,0.f,0.f,0.f},{0.f,0.f,0.f,0.f}};

  float4 pv[4];   // P prefetch: 64 i rows x 16 float4 (j)
  uint4  xv[4];   // X prefetch: 128 c rows x 8 uint4 (j)

#pragma unroll
  for (int r = 0; r < 4; ++r) {
    int li = tid + 256 * r;
    { int ii = li >> 4, f4 = li & 15;
      pv[r] = *(const float4*)&pA[(size_t)ii * S_ + f4 * 4]; }
    { int cc = li >> 3, p8 = li & 7;
      xv[r] = *(const uint4*)&xA[(size_t)cc * S_ + p8 * 8]; }
  }

  for (int t = 0; t < 16; ++t) {
    __syncthreads();   // previous-iteration LDS reads done
#pragma unroll
    for (int r = 0; r < 4; ++r) {
      int li = tid + 256 * r;
      int ii = li >> 4, f4 = li & 15;
      *(bf16x4*)&Ps[ii * 72 + f4 * 4] = cvt4(pv[r]);
    }
#pragma unroll
    for (int r = 0; r < 4; ++r) {
      int li = tid + 256 * r;
      int cc = li >> 3, p8 = li & 7;
      *(uint4*)&Xs[cc * 72 + p8 * 8] = xv[r];
    }
    __syncthreads();   // tile ready
    if (t < 15) {      // issue next-tile loads; overlap with MFMAs below
      const int j1 = (t + 1) * 64;
#pragma unroll
      for (int r = 0; r < 4; ++r) {
        int li = tid + 256 * r;
        { int ii = li >> 4, f4 = li & 15;
          pv[r] = *(const float4*)&pA[(size_t)ii * S_ + j1 + f4 * 4]; }
        { int cc = li >> 3, p8 = li & 7;
          xv[r] = *(const uint4*)&xA[(size_t)cc * S_ + j1 + p8 * 8]; }
      }
    }
#pragma unroll
    for (int ks = 0; ks < 2; ++ks) {
      bf16x8 aF = *(const bf16x8*)&Ps[(w * 16 + col) * 72 + ks * 32 + quad * 8];
#pragma unroll
      for (int s = 0; s < 8; ++s) {
        bf16x8 bF = *(const bf16x8*)&Xs[(s * 16 + col) * 72 + ks * 32 + quad * 8];
        acc[s] = __builtin_amdgcn_mfma_f32_16x16x32_bf16(aF, bF, acc[s], 0, 0, 0);
      }
    }
  }

#pragma unroll
  for (int s = 0; s < 8; ++s) {
    const int c = c0 + s * 16 + col;
#pragma unroll
    for (int r = 0; r < 4; ++r) {
      const int i = i0 + w * 16 + quad * 4 + r;
      out[(size_t)(b * S_ + i) * D_ + c] = acc[s][r];
    }
  }
}

extern "C" void kernel_launch(void* const* d_in, const int* in_sizes, int n_in,
                              void* d_out, int out_size, void* d_ws, size_t ws_size,
                              hipStream_t stream) {
  const float* x  = (const float*)d_in[0];
  const float* qw = (const float*)d_in[1];
  const float* qb = (const float*)d_in[2];
  const float* kw = (const float*)d_in[3];
  const float* ab = (const float*)d_in[4];

  float* out  = (float*)d_out;
  float* attn = out + (size_t)B_ * S_ * D_;          // outputs concatenated

  unsigned short* Qb = (unsigned short*)d_ws;        // bf16 Q [B][S][64]
  unsigned short* Kb = Qb + (size_t)B_ * S_ * QK_;   // bf16 K [B][S][64]
  unsigned short* Xt = Kb + (size_t)B_ * S_ * QK_;   // bf16 X^T [B][384][1024]

  k_proj <<<2 * S_,       256, 0, stream>>>(x, qw, qb, kw, Qb, Kb);
  k_xt   <<<B_ * 32 * 12, 256, 0, stream>>>(x, Xt);
  k_attn <<<B_ * 64,      256, 0, stream>>>(Qb, Kb, ab, attn);
  k_out  <<<B_ * 16 * 3,  256, 0, stream>>>(attn, Xt, out);
}